// Round 10
// baseline (515.629 us; speedup 1.0000x reference)
//
#include <hip/hip_runtime.h>
#include <hip/hip_bf16.h>

#define BDIM 4
#define NSEQ 4096
#define DHEAD 128
#define SCALE 0.08838834764831845f

typedef __bf16 bf16x8 __attribute__((ext_vector_type(8)));
typedef float f32x4 __attribute__((ext_vector_type(4)));
typedef float f32x16 __attribute__((ext_vector_type(16)));
typedef unsigned int u32x4 __attribute__((ext_vector_type(4)));

__device__ __forceinline__ unsigned short f2bf(float f){
    return __builtin_bit_cast(unsigned short, (__bf16)f);
}
__device__ __forceinline__ unsigned long long pack4(float4 u){
    return (unsigned long long)f2bf(u.x)
         | ((unsigned long long)f2bf(u.y) << 16)
         | ((unsigned long long)f2bf(u.z) << 32)
         | ((unsigned long long)f2bf(u.w) << 48);
}
__device__ __forceinline__ void gload_lds16(const void* g, void* l){
    __builtin_amdgcn_global_load_lds(
        (const __attribute__((address_space(1))) unsigned int*)g,
        (__attribute__((address_space(3))) unsigned int*)l, 16, 0, 0);
}

// ---------------------------------------------------------------------------
// Fused kernel A: blocks [0,1024) = softmax stats (proven attn_stats body);
// blocks [1024,1536) = repack K,V -> frag-major 32x32x16 images (proven
// repack3 body).  Stats partials at pbase = ws+8MB; images at ws[0,8MB).
// ---------------------------------------------------------------------------
extern "C" __global__ __launch_bounds__(256, 4)
void stats_repack(const float* __restrict__ K, const float* __restrict__ Q,
                  const float* __restrict__ V, char* __restrict__ ws)
{
    const int bid0 = blockIdx.x;
    const int tid = threadIdx.x;

    if (bid0 >= 1024) {
        // ================= repack path =================
        const int rid = bid0 - 1024;     // 4b * 128T
        const int T = rid & 127;
        const int b = rid >> 7;

        char* Kp = ws + ((size_t)(b * 128 + T) << 14);
        const float* Ks = K + ((size_t)b * NSEQ + T * 32) * DHEAD;
        const float* Vs = V + ((size_t)b * NSEQ + T * 32) * DHEAD;

#pragma unroll
        for (int i = 0; i < 2; i++) {
            int u = tid + 256 * i;
            int ds = u >> 6, ln = u & 63;
            int m = ln & 31, hi = ln >> 5;
            const float* s = Ks + (size_t)m * DHEAD + ds * 16 + hi * 8;
            float4 a = *(const float4*)s;
            float4 bq = *(const float4*)(s + 4);
            ulonglong2 wv;
            wv.x = pack4(a);
            wv.y = pack4(bq);
            *(ulonglong2*)(Kp + u * 16) = wv;
        }
#pragma unroll
        for (int i = 0; i < 2; i++) {
            int u = tid + 256 * i;
            int f = u >> 6, ln = u & 63;
            int dg = f >> 1, kb = f & 1;
            int dd = ln & 31, hi = ln >> 5;
            int d = dg * 32 + dd;
            const float* s = Vs + (size_t)(kb * 16 + hi * 8) * DHEAD + d;
            float v0 = s[0 * DHEAD], v1 = s[1 * DHEAD], v2 = s[2 * DHEAD], v3 = s[3 * DHEAD];
            float v4 = s[4 * DHEAD], v5 = s[5 * DHEAD], v6 = s[6 * DHEAD], v7 = s[7 * DHEAD];
            ulonglong2 wv;
            wv.x = (unsigned long long)f2bf(v0)
                 | ((unsigned long long)f2bf(v1) << 16)
                 | ((unsigned long long)f2bf(v2) << 32)
                 | ((unsigned long long)f2bf(v3) << 48);
            wv.y = (unsigned long long)f2bf(v4)
                 | ((unsigned long long)f2bf(v5) << 16)
                 | ((unsigned long long)f2bf(v6) << 32)
                 | ((unsigned long long)f2bf(v7) << 48);
            *(ulonglong2*)(Kp + 8192 + u * 16) = wv;
        }
        return;
    }

    // ================= stats path =================
    __shared__ __align__(16) char Klds[64 * 256];

    float* pbase = (float*)(ws + (8u << 20));
    const int bid = bid0;
    const int ks  = bid & 3;
    const int rt  = (bid >> 2) & 63;
    const int b   = bid >> 8;
    const int lane = tid & 63;
    const int w    = tid >> 6;
    const int g    = lane >> 4;
    const int c    = lane & 15;
    const int rowbase = rt * 64;

    const float* qrow = Q + ((size_t)b * NSEQ + rowbase + w * 16 + c) * DHEAD;
    bf16x8 qf[4];
#pragma unroll
    for (int kk = 0; kk < 4; kk++) {
        const float4* p0 = (const float4*)(qrow + g * 8 + kk * 32);
        float4 u = p0[0], v = p0[1];
        bf16x8 t;
        t[0] = (__bf16)(u.x * SCALE); t[1] = (__bf16)(u.y * SCALE);
        t[2] = (__bf16)(u.z * SCALE); t[3] = (__bf16)(u.w * SCALE);
        t[4] = (__bf16)(v.x * SCALE); t[5] = (__bf16)(v.y * SCALE);
        t[6] = (__bf16)(v.z * SCALE); t[7] = (__bf16)(v.w * SCALE);
        qf[kk] = t;
    }

    float m[4], l[4];
#pragma unroll
    for (int r = 0; r < 4; r++) { m[r] = -1e30f; l[r] = 0.0f; }

    const int f  = tid & 31;
    const int r0 = tid >> 5;

    for (int kt = 0; kt < 16; kt++) {
        const float* ktile = K + ((size_t)b * NSEQ + ks * 1024 + kt * 64) * DHEAD;
#pragma unroll
        for (int i = 0; i < 8; i++) {
            int r = r0 + i * 8;
            float4 u = *(const float4*)(ktile + (size_t)r * DHEAD + f * 4);
            *(unsigned long long*)(Klds + r * 256 + ((f * 8) ^ ((r & 7) << 4))) = pack4(u);
        }
        __syncthreads();

        f32x4 acc[4];
#pragma unroll
        for (int n = 0; n < 4; n++) acc[n] = (f32x4){0.f, 0.f, 0.f, 0.f};
#pragma unroll
        for (int n = 0; n < 4; n++) {
            int row = n * 16 + c;
#pragma unroll
            for (int kk = 0; kk < 4; kk++) {
                bf16x8 kf = *(const bf16x8*)(Klds + row * 256 +
                                ((g * 16 + kk * 64) ^ ((row & 7) << 4)));
                acc[n] = __builtin_amdgcn_mfma_f32_16x16x32_bf16(qf[kk], kf, acc[n], 0, 0, 0);
            }
        }

#pragma unroll
        for (int r = 0; r < 4; r++) {
            float t = fmaxf(fmaxf(acc[0][r], acc[1][r]), fmaxf(acc[2][r], acc[3][r]));
            t = fmaxf(t, __shfl_xor(t, 1));
            t = fmaxf(t, __shfl_xor(t, 2));
            t = fmaxf(t, __shfl_xor(t, 4));
            t = fmaxf(t, __shfl_xor(t, 8));
            float mn = fmaxf(m[r], t);
            float sc = __expf(m[r] - mn);
            float ps = __expf(acc[0][r] - mn) + __expf(acc[1][r] - mn)
                     + __expf(acc[2][r] - mn) + __expf(acc[3][r] - mn);
            ps += __shfl_xor(ps, 1);
            ps += __shfl_xor(ps, 2);
            ps += __shfl_xor(ps, 4);
            ps += __shfl_xor(ps, 8);
            l[r] = l[r] * sc + ps;
            m[r] = mn;
        }
        __syncthreads();
    }

    if (c == 0) {
#pragma unroll
        for (int r = 0; r < 4; r++) {
            size_t row = rowbase + w * 16 + g * 4 + r;
            float* p = pbase + ((size_t)b * NSEQ + row) * 8 + ks * 2;
            p[0] = m[r];
            p[1] = l[r];
        }
    }
}

// ---------------------------------------------------------------------------
// Kernel 2: 32x32x16 finalize (R9 core, verified).  grid 1024 (ks=8),
// 256 thr (4 waves), 3 blocks/CU.  ctx partials -> atomicAdd on zeroed ctx.
// ---------------------------------------------------------------------------
extern "C" __global__ __launch_bounds__(256, 3)
void attn_mf2(const char* __restrict__ ws, const float* __restrict__ Q,
              float* __restrict__ out)
{
    __shared__ __align__(16) char LDS[32768];

    const int bid = blockIdx.x;
    const int ks  = bid & 7;
    const int qt  = (bid >> 3) & 31;
    const int b   = bid >> 8;
    const int tid = threadIdx.x;
    const int wv  = tid >> 6;
    const int lane = tid & 63;
    const int hi   = lane >> 5;
    const int qq   = lane & 31;
    const int q    = qt * 128 + wv * 32 + qq;

    float* attn = out + (size_t)BDIM * NSEQ * DHEAD;
    const float* pb = (const float*)(ws + (8u << 20));

    float Cq;
    {
        const float* prow = pb + ((size_t)b * NSEQ + q) * 8;
        float4 p0 = *(const float4*)prow;
        float4 p1 = *(const float4*)(prow + 4);
        float M = fmaxf(fmaxf(p0.x, p0.z), fmaxf(p1.x, p1.z));
        float L = p0.y * __expf(p0.x - M) + p0.w * __expf(p0.z - M)
                + p1.y * __expf(p1.x - M) + p1.w * __expf(p1.z - M);
        Cq = M + __logf(L);
    }

    const float* qrow = Q + ((size_t)b * NSEQ + q) * DHEAD;
    bf16x8 qf[8];
#pragma unroll
    for (int ds = 0; ds < 8; ds++) {
        const float4* p0 = (const float4*)(qrow + ds * 16 + hi * 8);
        float4 u = p0[0], v = p0[1];
        bf16x8 t;
        t[0] = (__bf16)(u.x * SCALE); t[1] = (__bf16)(u.y * SCALE);
        t[2] = (__bf16)(u.z * SCALE); t[3] = (__bf16)(u.w * SCALE);
        t[4] = (__bf16)(v.x * SCALE); t[5] = (__bf16)(v.y * SCALE);
        t[6] = (__bf16)(v.z * SCALE); t[7] = (__bf16)(v.w * SCALE);
        qf[ds] = t;
    }

    f32x16 ctx[4];
#pragma unroll
    for (int dg = 0; dg < 4; dg++) ctx[dg] = (f32x16)(0.0f);

    const char* img = ws + ((size_t)(b * 128 + ks * 16) << 14);   // 16 tiles

#pragma unroll
    for (int i = 0; i < 4; i++) {
        int o = tid * 16 + i * 4096;
        gload_lds16(img + o, LDS + o);
    }

    float* arowb = attn + ((size_t)b * NSEQ + q) * NSEQ + ks * 512 + 4 * hi;

    for (int kt = 0; kt < 16; kt++) {
        __builtin_amdgcn_s_barrier();
        __builtin_amdgcn_sched_barrier(0);
        if (kt < 15) {
            const char* src = img + ((size_t)(kt + 1) << 14);
            char* dst = LDS + (((kt + 1) & 1) << 14);
#pragma unroll
            for (int i = 0; i < 4; i++) {
                int o = tid * 16 + i * 4096;
                gload_lds16(src + o, dst + o);
            }
            asm volatile("s_waitcnt vmcnt(4)" ::: "memory");
        } else {
            asm volatile("s_waitcnt vmcnt(0)" ::: "memory");
        }
        __builtin_amdgcn_s_barrier();
        __builtin_amdgcn_sched_barrier(0);

        const char* bufc = LDS + ((kt & 1) << 14);

        // ---- S^T = K Q^T : two interleaved 4-deep chains ----
        f32x16 s0 = (f32x16)(0.0f), s1 = (f32x16)(0.0f);
        __builtin_amdgcn_s_setprio(1);
#pragma unroll
        for (int dp = 0; dp < 4; dp++) {
            bf16x8 kfa = *(const bf16x8*)(bufc + (2 * dp) * 1024 + lane * 16);
            bf16x8 kfb = *(const bf16x8*)(bufc + (2 * dp + 1) * 1024 + lane * 16);
            s0 = __builtin_amdgcn_mfma_f32_32x32x16_bf16(kfa, qf[2 * dp], s0, 0, 0, 0);
            s1 = __builtin_amdgcn_mfma_f32_32x32x16_bf16(kfb, qf[2 * dp + 1], s1, 0, 0, 0);
        }
        __builtin_amdgcn_s_setprio(0);

        // ---- P = exp(s - C); attn stores; pack for PV ----
        float p[16];
#pragma unroll
        for (int r = 0; r < 16; r++) p[r] = __expf((s0[r] + s1[r]) - Cq);

        float* arow = arowb + kt * 32;
#pragma unroll
        for (int j = 0; j < 4; j++) {
            float4 pv = {p[4 * j], p[4 * j + 1], p[4 * j + 2], p[4 * j + 3]};
            *(float4*)(arow + 8 * j) = pv;
        }

        unsigned int bpk[8], sb[8];
#pragma unroll
        for (int i = 0; i < 8; i++)
            bpk[i] = (unsigned int)f2bf(p[2 * i]) | ((unsigned int)f2bf(p[2 * i + 1]) << 16);
#pragma unroll
        for (int i = 0; i < 8; i++)
            sb[i] = (unsigned int)__shfl_xor((int)bpk[i], 32);

        u32x4 w0, w1;
        w0[0] = hi ? sb[2] : bpk[0];
        w0[1] = hi ? sb[3] : bpk[1];
        w0[2] = hi ? bpk[2] : sb[0];
        w0[3] = hi ? bpk[3] : sb[1];
        w1[0] = hi ? sb[6] : bpk[4];
        w1[1] = hi ? sb[7] : bpk[5];
        w1[2] = hi ? bpk[6] : sb[4];
        w1[3] = hi ? bpk[7] : sb[5];
        bf16x8 pf0 = __builtin_bit_cast(bf16x8, w0);
        bf16x8 pf1 = __builtin_bit_cast(bf16x8, w1);

        // ---- ctx += P V ----
        __builtin_amdgcn_s_setprio(1);
#pragma unroll
        for (int dg = 0; dg < 4; dg++) {
            bf16x8 vf0 = *(const bf16x8*)(bufc + 8192 + (dg * 2 + 0) * 1024 + lane * 16);
            bf16x8 vf1 = *(const bf16x8*)(bufc + 8192 + (dg * 2 + 1) * 1024 + lane * 16);
            ctx[dg] = __builtin_amdgcn_mfma_f32_32x32x16_bf16(vf0, pf0, ctx[dg], 0, 0, 0);
            ctx[dg] = __builtin_amdgcn_mfma_f32_32x32x16_bf16(vf1, pf1, ctx[dg], 0, 0, 0);
        }
        __builtin_amdgcn_s_setprio(0);
    }

    // ---- epilogue: 8-way ks combine via atomics on zeroed ctx ----
    float* cp = out + ((size_t)b * NSEQ + q) * DHEAD + 4 * hi;
#pragma unroll
    for (int dg = 0; dg < 4; dg++)
#pragma unroll
        for (int j = 0; j < 4; j++)
#pragma unroll
            for (int e = 0; e < 4; e++)
                atomicAdd(cp + dg * 32 + 8 * j + e, ctx[dg][4 * j + e]);
}

// ---------------------------------------------------------------------------
// Fallback pair (proven R4; partials in attn cols 0..7).
// ---------------------------------------------------------------------------
extern "C" __global__ __launch_bounds__(256, 4)
void attn_stats_fb(const float* __restrict__ K, const float* __restrict__ Q,
                   float* __restrict__ pbase, int pstride)
{
    __shared__ __align__(16) char Klds[64 * 256];

    const int bid = blockIdx.x;
    const int ks  = bid & 3;
    const int rt  = (bid >> 2) & 63;
    const int b   = bid >> 8;
    const int tid = threadIdx.x;
    const int lane = tid & 63;
    const int w    = tid >> 6;
    const int g    = lane >> 4;
    const int c    = lane & 15;
    const int rowbase = rt * 64;

    const float* qrow = Q + ((size_t)b * NSEQ + rowbase + w * 16 + c) * DHEAD;
    bf16x8 qf[4];
#pragma unroll
    for (int kk = 0; kk < 4; kk++) {
        const float4* p0 = (const float4*)(qrow + g * 8 + kk * 32);
        float4 u = p0[0], v = p0[1];
        bf16x8 t;
        t[0] = (__bf16)(u.x * SCALE); t[1] = (__bf16)(u.y * SCALE);
        t[2] = (__bf16)(u.z * SCALE); t[3] = (__bf16)(u.w * SCALE);
        t[4] = (__bf16)(v.x * SCALE); t[5] = (__bf16)(v.y * SCALE);
        t[6] = (__bf16)(v.z * SCALE); t[7] = (__bf16)(v.w * SCALE);
        qf[kk] = t;
    }

    float m[4], l[4];
#pragma unroll
    for (int r = 0; r < 4; r++) { m[r] = -1e30f; l[r] = 0.0f; }

    const int f  = tid & 31;
    const int r0 = tid >> 5;

    for (int kt = 0; kt < 16; kt++) {
        const float* ktile = K + ((size_t)b * NSEQ + ks * 1024 + kt * 64) * DHEAD;
#pragma unroll
        for (int i = 0; i < 8; i++) {
            int r = r0 + i * 8;
            float4 u = *(const float4*)(ktile + (size_t)r * DHEAD + f * 4);
            *(unsigned long long*)(Klds + r * 256 + ((f * 8) ^ ((r & 7) << 4))) = pack4(u);
        }
        __syncthreads();

        f32x4 acc[4];
#pragma unroll
        for (int n = 0; n < 4; n++) acc[n] = (f32x4){0.f, 0.f, 0.f, 0.f};
#pragma unroll
        for (int n = 0; n < 4; n++) {
            int row = n * 16 + c;
#pragma unroll
            for (int kk = 0; kk < 4; kk++) {
                bf16x8 kf = *(const bf16x8*)(Klds + row * 256 +
                                ((g * 16 + kk * 64) ^ ((row & 7) << 4)));
                acc[n] = __builtin_amdgcn_mfma_f32_16x16x32_bf16(qf[kk], kf, acc[n], 0, 0, 0);
            }
        }

#pragma unroll
        for (int r = 0; r < 4; r++) {
            float t = fmaxf(fmaxf(acc[0][r], acc[1][r]), fmaxf(acc[2][r], acc[3][r]));
            t = fmaxf(t, __shfl_xor(t, 1));
            t = fmaxf(t, __shfl_xor(t, 2));
            t = fmaxf(t, __shfl_xor(t, 4));
            t = fmaxf(t, __shfl_xor(t, 8));
            float mn = fmaxf(m[r], t);
            float sc = __expf(m[r] - mn);
            float ps = __expf(acc[0][r] - mn) + __expf(acc[1][r] - mn)
                     + __expf(acc[2][r] - mn) + __expf(acc[3][r] - mn);
            ps += __shfl_xor(ps, 1);
            ps += __shfl_xor(ps, 2);
            ps += __shfl_xor(ps, 4);
            ps += __shfl_xor(ps, 8);
            l[r] = l[r] * sc + ps;
            m[r] = mn;
        }
        __syncthreads();
    }

    if (c == 0) {
#pragma unroll
        for (int r = 0; r < 4; r++) {
            size_t row = rowbase + w * 16 + g * 4 + r;
            float* p = pbase + ((size_t)b * NSEQ + row) * pstride + ks * 2;
            p[0] = m[r];
            p[1] = l[r];
        }
    }
}

extern "C" __global__ __launch_bounds__(512, 2)
void attn_final_fb(const float* __restrict__ K, const float* __restrict__ Q,
                   const float* __restrict__ V, float* __restrict__ out)
{
    __shared__ __align__(16) char LDS[81920];

    const int bid = blockIdx.x;
    const int rt  = bid & 63;
    const int b   = bid >> 6;
    const int tid = threadIdx.x;
    const int rowbase = rt * 64;
    const int lane = tid & 63;
    const int w    = tid >> 6;
    const int rw   = w & 3;
    const int grp  = w >> 2;
    const int g    = lane >> 4;
    const int c    = lane & 15;
    const int t    = tid & 255;

    float* ctxOut = out;
    float* attn   = out + (size_t)BDIM * NSEQ * DHEAD;

    char* Klds  = LDS + grp * 16384;
    char* Vtlds = LDS + 32768 + grp * 16384;
    char* Plds  = LDS + 65536 + w * 2048;

    float Cq;
    {
        const float* prow = attn + ((size_t)b * NSEQ + rowbase + rw * 16 + c) * NSEQ;
        float4 p0 = *(const float4*)prow;
        float4 p1 = *(const float4*)(prow + 4);
        float M = fmaxf(fmaxf(p0.x, p0.z), fmaxf(p1.x, p1.z));
        float L = p0.y * __expf(p0.x - M) + p0.w * __expf(p0.z - M)
                + p1.y * __expf(p1.x - M) + p1.w * __expf(p1.z - M);
        Cq = M + __logf(L);
    }

    const float* qrow = Q + ((size_t)b * NSEQ + rowbase + rw * 16 + c) * DHEAD;
    bf16x8 qf[4];
#pragma unroll
    for (int kk = 0; kk < 4; kk++) {
        const float4* p0 = (const float4*)(qrow + g * 8 + kk * 32);
        float4 u = p0[0], v = p0[1];
        bf16x8 tt;
        tt[0] = (__bf16)(u.x * SCALE); tt[1] = (__bf16)(u.y * SCALE);
        tt[2] = (__bf16)(u.z * SCALE); tt[3] = (__bf16)(u.w * SCALE);
        tt[4] = (__bf16)(v.x * SCALE); tt[5] = (__bf16)(v.y * SCALE);
        tt[6] = (__bf16)(v.z * SCALE); tt[7] = (__bf16)(v.w * SCALE);
        qf[kk] = tt;
    }

    f32x4 ctx[8];
#pragma unroll
    for (int n2 = 0; n2 < 8; n2++) ctx[n2] = (f32x4){0.f, 0.f, 0.f, 0.f};

    __syncthreads();

    const int fK = t & 31;
    const int rK = t >> 5;
    const int dq = t & 15;
    const int kb = t >> 4;
    const int k0 = kb * 4;
    const int d0 = dq * 2;

    const float* kbase = K + ((size_t)b * NSEQ + grp * 2048) * DHEAD;
    const float* vbase = V + ((size_t)b * NSEQ + grp * 2048) * DHEAD;

    float4 kreg[8];
    float2 vreg[4][4];

#pragma unroll
    for (int i = 0; i < 8; i++)
        kreg[i] = *(const float4*)(kbase + (size_t)(rK + i * 8) * DHEAD + fK * 4);
#pragma unroll
    for (int i = 0; i < 4; i++)
#pragma unroll
        for (int j = 0; j < 4; j++)
            vreg[i][j] = *(const float2*)(vbase + (size_t)(k0 + j) * DHEAD + d0 + 32 * i);

    for (int kt = 0; kt < 32; kt++) {
        __builtin_amdgcn_s_barrier();

#pragma unroll
        for (int i = 0; i < 8; i++) {
            int row = rK + i * 8;
            *(unsigned long long*)(Klds + row * 256 + ((fK * 8) ^ ((row & 7) << 4))) = pack4(kreg[i]);
        }
#pragma unroll
        for (int i = 0; i < 4; i++) {
            int d = d0 + 32 * i;
            unsigned long long rr0 =
                (unsigned long long)f2bf(vreg[i][0].x)
              | ((unsigned long long)f2bf(vreg[i][1].x) << 16)
              | ((unsigned long long)f2bf(vreg[i][2].x) << 32)
              | ((unsigned long long)f2bf(vreg[i][3].x) << 48);
            unsigned long long rr1 =
                (unsigned long long)f2bf(vreg[i][0].y)
              | ((unsigned long long)f2bf(vreg[i][1].y) << 16)
              | ((unsigned long long)f2bf(vreg[i][2].y) << 32)
              | ((unsigned long long)f2bf(vreg[i][3].y) << 48);
            int swz = (d & 7) << 4;
            *(unsigned long long*)(Vtlds + d * 128 + ((k0 * 2) ^ swz)) = rr0;
            *(unsigned long long*)(Vtlds + (d + 1) * 128 + ((k0 * 2) ^ (swz + 16))) = rr1;
        }
        asm volatile("s_waitcnt lgkmcnt(0)" ::: "memory");
        __builtin_amdgcn_s_barrier();

        {
            int kn = (kt + 1) & 31;
            const float* kp = kbase + (size_t)kn * 64 * DHEAD;
            const float* vp = vbase + (size_t)kn * 64 * DHEAD;
#pragma unroll
            for (int i = 0; i < 8; i++)
                kreg[i] = *(const float4*)(kp + (size_t)(rK + i * 8) * DHEAD + fK * 4);
#pragma unroll
            for (int i = 0; i < 4; i++)
#pragma unroll
                for (int j = 0; j < 4; j++)
                    vreg[i][j] = *(const float2*)(vp + (size_t)(k0 + j) * DHEAD + d0 + 32 * i);
        }

        f32x4 sacc[4];
#pragma unroll
        for (int nt = 0; nt < 4; nt++) sacc[nt] = (f32x4){0.f, 0.f, 0.f, 0.f};
        __builtin_amdgcn_s_setprio(1);
#pragma unroll
        for (int nt = 0; nt < 4; nt++) {
            int row = nt * 16 + c;
#pragma unroll
            for (int kk = 0; kk < 4; kk++) {
                bf16x8 kf = *(const bf16x8*)(Klds + row * 256 +
                                ((g * 16 + kk * 64) ^ ((row & 7) << 4)));
                sacc[nt] = __builtin_amdgcn_mfma_f32_16x16x32_bf16(kf, qf[kk], sacc[nt], 0, 0, 0);
            }
        }
        __builtin_amdgcn_s_setprio(0);

        const int col0 = grp * 2048 + kt * 64;
        float* arow = attn + ((size_t)b * NSEQ + rowbase + rw * 16 + c) * NSEQ + col0;
#pragma unroll
        for (int nt = 0; nt < 4; nt++) {
            float4 pv;
            pv.x = __expf(sacc[nt][0] - Cq);
            pv.y = __expf(sacc[nt][1] - Cq);
            pv.z = __expf(sacc[nt][2] - Cq);
            pv.w = __expf(sacc[nt][3] - Cq);
            *(float4*)(arow + nt * 16 + g * 4) = pv;
            *(unsigned long long*)(Plds + c * 128 +
                ((nt * 32 + g * 8) ^ ((c & 7) << 4))) = pack4(pv);
        }
        asm volatile("s_waitcnt lgkmcnt(0)" ::: "memory");
        __builtin_amdgcn_sched_barrier(0);

        bf16x8 pf[2];
#pragma unroll
        for (int kk = 0; kk < 2; kk++)
            pf[kk] = *(const bf16x8*)(Plds + c * 128 +
                        ((kk * 64 + g * 16) ^ ((c & 7) << 4)));

        __builtin_amdgcn_s_setprio(1);
#pragma unroll
        for (int n2 = 0; n2 < 8; n2++) {
            int d = n2 * 16 + c;
#pragma unroll
            for (int kk = 0; kk < 2; kk++) {
                bf16x8 vff = *(const bf16x8*)(Vtlds + d * 128 +
                                ((kk * 64 + g * 16) ^ ((d & 7) << 4)));
                ctx[n2] = __builtin_amdgcn_mfma_f32_16x16x32_bf16(pf[kk], vff, ctx[n2], 0, 0, 0);
            }
        }
        __builtin_amdgcn_s_setprio(0);
    }

    __syncthreads();

    float* red = (float*)LDS;
    if (grp == 1) {
#pragma unroll
        for (int n2 = 0; n2 < 8; n2++)
#pragma unroll
            for (int r = 0; r < 4; r++)
                red[(rw * 16 + g * 4 + r) * 128 + n2 * 16 + c] = ctx[n2][r];
    }
    __syncthreads();
    if (grp == 0) {
#pragma unroll
        for (int n2 = 0; n2 < 8; n2++)
#pragma unroll
            for (int r = 0; r < 4; r++) {
                size_t row = rowbase + rw * 16 + g * 4 + r;
                ctxOut[((size_t)b * NSEQ + row) * DHEAD + n2 * 16 + c] =
                    ctx[n2][r] + red[(rw * 16 + g * 4 + r) * 128 + n2 * 16 + c];
            }
    }
}

extern "C" void kernel_launch(void* const* d_in, const int* in_sizes, int n_in,
                              void* d_out, int out_size, void* d_ws, size_t ws_size,
                              hipStream_t stream)
{
    const float* K = (const float*)d_in[0];   // "key"
    const float* Q = (const float*)d_in[1];   // "query"
    const float* V = (const float*)d_in[2];   // "value"
    float* out  = (float*)d_out;
    float* attn = out + (size_t)BDIM * NSEQ * DHEAD;

    const size_t ctx_bytes = (size_t)BDIM * NSEQ * DHEAD * sizeof(float);  // 8 MB
    const size_t need      = (9u << 20);                                   // images + partials

    if (ws_size >= need) {
        char* ws = (char*)d_ws;
        hipMemsetAsync(out, 0, ctx_bytes, stream);
        stats_repack<<<dim3(1024 + 512), dim3(256), 0, stream>>>(K, Q, V, ws);
        attn_mf2<<<dim3(1024), dim3(256), 0, stream>>>(ws, Q, out);
    } else {
        attn_stats_fb<<<dim3(4 * 64 * 4), dim3(256), 0, stream>>>(K, Q, attn, NSEQ);
        attn_final_fb<<<dim3(4 * 64), dim3(512), 0, stream>>>(K, Q, V, out);
    }
}

// Round 11
// 155.449 us; speedup vs baseline: 3.3170x; 3.3170x over previous
//
#include <hip/hip_runtime.h>
#include <hip/hip_bf16.h>

#define BDIM 4
#define NSEQ 4096
#define DHEAD 128
#define SCALE 0.08838834764831845f

typedef __bf16 bf16x8 __attribute__((ext_vector_type(8)));
typedef float f32x4 __attribute__((ext_vector_type(4)));
typedef float f32x16 __attribute__((ext_vector_type(16)));
typedef unsigned int u32x4 __attribute__((ext_vector_type(4)));

__device__ __forceinline__ unsigned short f2bf(float f){
    return __builtin_bit_cast(unsigned short, (__bf16)f);
}
__device__ __forceinline__ unsigned long long pack4(float4 u){
    return (unsigned long long)f2bf(u.x)
         | ((unsigned long long)f2bf(u.y) << 16)
         | ((unsigned long long)f2bf(u.z) << 32)
         | ((unsigned long long)f2bf(u.w) << 48);
}
__device__ __forceinline__ void gload_lds16(const void* g, void* l){
    __builtin_amdgcn_global_load_lds(
        (const __attribute__((address_space(1))) unsigned int*)g,
        (__attribute__((address_space(3))) unsigned int*)l, 16, 0, 0);
}

// ---------------------------------------------------------------------------
// Fused kernel A (proven R10): blocks [0,1024) = softmax stats;
// blocks [1024,1536) = repack K,V -> frag-major 32x32x16 images in ws.
// ---------------------------------------------------------------------------
extern "C" __global__ __launch_bounds__(256, 4)
void stats_repack(const float* __restrict__ K, const float* __restrict__ Q,
                  const float* __restrict__ V, char* __restrict__ ws)
{
    const int bid0 = blockIdx.x;
    const int tid = threadIdx.x;

    if (bid0 >= 1024) {
        // ================= repack path =================
        const int rid = bid0 - 1024;     // 4b * 128T
        const int T = rid & 127;
        const int b = rid >> 7;

        char* Kp = ws + ((size_t)(b * 128 + T) << 14);
        const float* Ks = K + ((size_t)b * NSEQ + T * 32) * DHEAD;
        const float* Vs = V + ((size_t)b * NSEQ + T * 32) * DHEAD;

#pragma unroll
        for (int i = 0; i < 2; i++) {
            int u = tid + 256 * i;
            int ds = u >> 6, ln = u & 63;
            int m = ln & 31, hi = ln >> 5;
            const float* s = Ks + (size_t)m * DHEAD + ds * 16 + hi * 8;
            float4 a = *(const float4*)s;
            float4 bq = *(const float4*)(s + 4);
            ulonglong2 wv;
            wv.x = pack4(a);
            wv.y = pack4(bq);
            *(ulonglong2*)(Kp + u * 16) = wv;
        }
#pragma unroll
        for (int i = 0; i < 2; i++) {
            int u = tid + 256 * i;
            int f = u >> 6, ln = u & 63;
            int dg = f >> 1, kb = f & 1;
            int dd = ln & 31, hi = ln >> 5;
            int d = dg * 32 + dd;
            const float* s = Vs + (size_t)(kb * 16 + hi * 8) * DHEAD + d;
            float v0 = s[0 * DHEAD], v1 = s[1 * DHEAD], v2 = s[2 * DHEAD], v3 = s[3 * DHEAD];
            float v4 = s[4 * DHEAD], v5 = s[5 * DHEAD], v6 = s[6 * DHEAD], v7 = s[7 * DHEAD];
            ulonglong2 wv;
            wv.x = (unsigned long long)f2bf(v0)
                 | ((unsigned long long)f2bf(v1) << 16)
                 | ((unsigned long long)f2bf(v2) << 32)
                 | ((unsigned long long)f2bf(v3) << 48);
            wv.y = (unsigned long long)f2bf(v4)
                 | ((unsigned long long)f2bf(v5) << 16)
                 | ((unsigned long long)f2bf(v6) << 32)
                 | ((unsigned long long)f2bf(v7) << 48);
            *(ulonglong2*)(Kp + 8192 + u * 16) = wv;
        }
        return;
    }

    // ================= stats path =================
    __shared__ __align__(16) char Klds[64 * 256];

    float* pbase = (float*)(ws + (8u << 20));
    const int bid = bid0;
    const int ks  = bid & 3;
    const int rt  = (bid >> 2) & 63;
    const int b   = bid >> 8;
    const int lane = tid & 63;
    const int w    = tid >> 6;
    const int g    = lane >> 4;
    const int c    = lane & 15;
    const int rowbase = rt * 64;

    const float* qrow = Q + ((size_t)b * NSEQ + rowbase + w * 16 + c) * DHEAD;
    bf16x8 qf[4];
#pragma unroll
    for (int kk = 0; kk < 4; kk++) {
        const float4* p0 = (const float4*)(qrow + g * 8 + kk * 32);
        float4 u = p0[0], v = p0[1];
        bf16x8 t;
        t[0] = (__bf16)(u.x * SCALE); t[1] = (__bf16)(u.y * SCALE);
        t[2] = (__bf16)(u.z * SCALE); t[3] = (__bf16)(u.w * SCALE);
        t[4] = (__bf16)(v.x * SCALE); t[5] = (__bf16)(v.y * SCALE);
        t[6] = (__bf16)(v.z * SCALE); t[7] = (__bf16)(v.w * SCALE);
        qf[kk] = t;
    }

    float m[4], l[4];
#pragma unroll
    for (int r = 0; r < 4; r++) { m[r] = -1e30f; l[r] = 0.0f; }

    const int f  = tid & 31;
    const int r0 = tid >> 5;

    for (int kt = 0; kt < 16; kt++) {
        const float* ktile = K + ((size_t)b * NSEQ + ks * 1024 + kt * 64) * DHEAD;
#pragma unroll
        for (int i = 0; i < 8; i++) {
            int r = r0 + i * 8;
            float4 u = *(const float4*)(ktile + (size_t)r * DHEAD + f * 4);
            *(unsigned long long*)(Klds + r * 256 + ((f * 8) ^ ((r & 7) << 4))) = pack4(u);
        }
        __syncthreads();

        f32x4 acc[4];
#pragma unroll
        for (int n = 0; n < 4; n++) acc[n] = (f32x4){0.f, 0.f, 0.f, 0.f};
#pragma unroll
        for (int n = 0; n < 4; n++) {
            int row = n * 16 + c;
#pragma unroll
            for (int kk = 0; kk < 4; kk++) {
                bf16x8 kf = *(const bf16x8*)(Klds + row * 256 +
                                ((g * 16 + kk * 64) ^ ((row & 7) << 4)));
                acc[n] = __builtin_amdgcn_mfma_f32_16x16x32_bf16(qf[kk], kf, acc[n], 0, 0, 0);
            }
        }

#pragma unroll
        for (int r = 0; r < 4; r++) {
            float t = fmaxf(fmaxf(acc[0][r], acc[1][r]), fmaxf(acc[2][r], acc[3][r]));
            t = fmaxf(t, __shfl_xor(t, 1));
            t = fmaxf(t, __shfl_xor(t, 2));
            t = fmaxf(t, __shfl_xor(t, 4));
            t = fmaxf(t, __shfl_xor(t, 8));
            float mn = fmaxf(m[r], t);
            float sc = __expf(m[r] - mn);
            float ps = __expf(acc[0][r] - mn) + __expf(acc[1][r] - mn)
                     + __expf(acc[2][r] - mn) + __expf(acc[3][r] - mn);
            ps += __shfl_xor(ps, 1);
            ps += __shfl_xor(ps, 2);
            ps += __shfl_xor(ps, 4);
            ps += __shfl_xor(ps, 8);
            l[r] = l[r] * sc + ps;
            m[r] = mn;
        }
        __syncthreads();
    }

    if (c == 0) {
#pragma unroll
        for (int r = 0; r < 4; r++) {
            size_t row = rowbase + w * 16 + g * 4 + r;
            float* p = pbase + ((size_t)b * NSEQ + row) * 8 + ks * 2;
            p[0] = m[r];
            p[1] = l[r];
        }
    }
}

// ---------------------------------------------------------------------------
// Kernel 2: 32x32x16 finalize (R9 core, verified).  grid 1024 (ks=8),
// 256 thr (4 waves), 3 blocks/CU.  ctx partials -> DENSE stores to ws
// (no atomics — R10 showed 8-way scalar atomics cost ~350 us).
// ---------------------------------------------------------------------------
extern "C" __global__ __launch_bounds__(256, 3)
void attn_mf2(const char* __restrict__ ws, const float* __restrict__ Q,
              float* __restrict__ out, float* __restrict__ part)
{
    __shared__ __align__(16) char LDS[32768];

    const int bid = blockIdx.x;
    const int ks  = bid & 7;
    const int qt  = (bid >> 3) & 31;
    const int b   = bid >> 8;
    const int tid = threadIdx.x;
    const int wv  = tid >> 6;
    const int lane = tid & 63;
    const int hi   = lane >> 5;
    const int qq   = lane & 31;
    const int q    = qt * 128 + wv * 32 + qq;

    float* attn = out + (size_t)BDIM * NSEQ * DHEAD;
    const float* pb = (const float*)(ws + (8u << 20));

    float Cq;
    {
        const float* prow = pb + ((size_t)b * NSEQ + q) * 8;
        float4 p0 = *(const float4*)prow;
        float4 p1 = *(const float4*)(prow + 4);
        float M = fmaxf(fmaxf(p0.x, p0.z), fmaxf(p1.x, p1.z));
        float L = p0.y * __expf(p0.x - M) + p0.w * __expf(p0.z - M)
                + p1.y * __expf(p1.x - M) + p1.w * __expf(p1.z - M);
        Cq = M + __logf(L);
    }

    const float* qrow = Q + ((size_t)b * NSEQ + q) * DHEAD;
    bf16x8 qf[8];
#pragma unroll
    for (int ds = 0; ds < 8; ds++) {
        const float4* p0 = (const float4*)(qrow + ds * 16 + hi * 8);
        float4 u = p0[0], v = p0[1];
        bf16x8 t;
        t[0] = (__bf16)(u.x * SCALE); t[1] = (__bf16)(u.y * SCALE);
        t[2] = (__bf16)(u.z * SCALE); t[3] = (__bf16)(u.w * SCALE);
        t[4] = (__bf16)(v.x * SCALE); t[5] = (__bf16)(v.y * SCALE);
        t[6] = (__bf16)(v.z * SCALE); t[7] = (__bf16)(v.w * SCALE);
        qf[ds] = t;
    }

    f32x16 ctx[4];
#pragma unroll
    for (int dg = 0; dg < 4; dg++) ctx[dg] = (f32x16)(0.0f);

    const char* img = ws + ((size_t)(b * 128 + ks * 16) << 14);   // 16 tiles

#pragma unroll
    for (int i = 0; i < 4; i++) {
        int o = tid * 16 + i * 4096;
        gload_lds16(img + o, LDS + o);
    }

    float* arowb = attn + ((size_t)b * NSEQ + q) * NSEQ + ks * 512 + 4 * hi;

    for (int kt = 0; kt < 16; kt++) {
        __builtin_amdgcn_s_barrier();
        __builtin_amdgcn_sched_barrier(0);
        if (kt < 15) {
            const char* src = img + ((size_t)(kt + 1) << 14);
            char* dst = LDS + (((kt + 1) & 1) << 14);
#pragma unroll
            for (int i = 0; i < 4; i++) {
                int o = tid * 16 + i * 4096;
                gload_lds16(src + o, dst + o);
            }
            asm volatile("s_waitcnt vmcnt(4)" ::: "memory");
        } else {
            asm volatile("s_waitcnt vmcnt(0)" ::: "memory");
        }
        __builtin_amdgcn_s_barrier();
        __builtin_amdgcn_sched_barrier(0);

        const char* bufc = LDS + ((kt & 1) << 14);

        // ---- S^T = K Q^T : two interleaved 4-deep chains ----
        f32x16 s0 = (f32x16)(0.0f), s1 = (f32x16)(0.0f);
        __builtin_amdgcn_s_setprio(1);
#pragma unroll
        for (int dp = 0; dp < 4; dp++) {
            bf16x8 kfa = *(const bf16x8*)(bufc + (2 * dp) * 1024 + lane * 16);
            bf16x8 kfb = *(const bf16x8*)(bufc + (2 * dp + 1) * 1024 + lane * 16);
            s0 = __builtin_amdgcn_mfma_f32_32x32x16_bf16(kfa, qf[2 * dp], s0, 0, 0, 0);
            s1 = __builtin_amdgcn_mfma_f32_32x32x16_bf16(kfb, qf[2 * dp + 1], s1, 0, 0, 0);
        }
        __builtin_amdgcn_s_setprio(0);

        // ---- P = exp(s - C); attn stores; pack for PV ----
        float p[16];
#pragma unroll
        for (int r = 0; r < 16; r++) p[r] = __expf((s0[r] + s1[r]) - Cq);

        float* arow = arowb + kt * 32;
#pragma unroll
        for (int j = 0; j < 4; j++) {
            float4 pv = {p[4 * j], p[4 * j + 1], p[4 * j + 2], p[4 * j + 3]};
            *(float4*)(arow + 8 * j) = pv;
        }

        unsigned int bpk[8], sb[8];
#pragma unroll
        for (int i = 0; i < 8; i++)
            bpk[i] = (unsigned int)f2bf(p[2 * i]) | ((unsigned int)f2bf(p[2 * i + 1]) << 16);
#pragma unroll
        for (int i = 0; i < 8; i++)
            sb[i] = (unsigned int)__shfl_xor((int)bpk[i], 32);

        u32x4 w0, w1;
        w0[0] = hi ? sb[2] : bpk[0];
        w0[1] = hi ? sb[3] : bpk[1];
        w0[2] = hi ? bpk[2] : sb[0];
        w0[3] = hi ? bpk[3] : sb[1];
        w1[0] = hi ? sb[6] : bpk[4];
        w1[1] = hi ? sb[7] : bpk[5];
        w1[2] = hi ? bpk[6] : sb[4];
        w1[3] = hi ? bpk[7] : sb[5];
        bf16x8 pf0 = __builtin_bit_cast(bf16x8, w0);
        bf16x8 pf1 = __builtin_bit_cast(bf16x8, w1);

        // ---- ctx += P V ----
        __builtin_amdgcn_s_setprio(1);
#pragma unroll
        for (int dg = 0; dg < 4; dg++) {
            bf16x8 vf0 = *(const bf16x8*)(bufc + 8192 + (dg * 2 + 0) * 1024 + lane * 16);
            bf16x8 vf1 = *(const bf16x8*)(bufc + 8192 + (dg * 2 + 1) * 1024 + lane * 16);
            ctx[dg] = __builtin_amdgcn_mfma_f32_32x32x16_bf16(vf0, pf0, ctx[dg], 0, 0, 0);
            ctx[dg] = __builtin_amdgcn_mfma_f32_32x32x16_bf16(vf1, pf1, ctx[dg], 0, 0, 0);
        }
        __builtin_amdgcn_s_setprio(0);
    }

    // ---- epilogue: dense float4 partial stores (deterministic) ----
    float* cp = part + (((size_t)(ks * 4 + b) * NSEQ + q) * DHEAD) + 4 * hi;
#pragma unroll
    for (int dg = 0; dg < 4; dg++)
#pragma unroll
        for (int j = 0; j < 4; j++) {
            float4 v = {ctx[dg][4 * j], ctx[dg][4 * j + 1],
                        ctx[dg][4 * j + 2], ctx[dg][4 * j + 3]};
            *(float4*)(cp + dg * 32 + 8 * j) = v;
        }
}

// ---------------------------------------------------------------------------
// Kernel 3: reduce the 8 ks-partials into ctx (deterministic).  (R9 proven)
// ---------------------------------------------------------------------------
extern "C" __global__ __launch_bounds__(256, 4)
void ctx_reduce8(const float4* __restrict__ part, float4* __restrict__ out)
{
    const size_t gt = (size_t)blockIdx.x * 256 + threadIdx.x;   // 524288 float4s
    const size_t stride = (size_t)BDIM * NSEQ * DHEAD / 4;
    float4 s = part[gt];
#pragma unroll
    for (int i = 1; i < 8; i++) {
        float4 a = part[gt + (size_t)i * stride];
        s.x += a.x; s.y += a.y; s.z += a.z; s.w += a.w;
    }
    out[gt] = s;
}

// ---------------------------------------------------------------------------
// Fallback pair (proven R4; partials in attn cols 0..7).
// ---------------------------------------------------------------------------
extern "C" __global__ __launch_bounds__(256, 4)
void attn_stats_fb(const float* __restrict__ K, const float* __restrict__ Q,
                   float* __restrict__ pbase, int pstride)
{
    __shared__ __align__(16) char Klds[64 * 256];

    const int bid = blockIdx.x;
    const int ks  = bid & 3;
    const int rt  = (bid >> 2) & 63;
    const int b   = bid >> 8;
    const int tid = threadIdx.x;
    const int lane = tid & 63;
    const int w    = tid >> 6;
    const int g    = lane >> 4;
    const int c    = lane & 15;
    const int rowbase = rt * 64;

    const float* qrow = Q + ((size_t)b * NSEQ + rowbase + w * 16 + c) * DHEAD;
    bf16x8 qf[4];
#pragma unroll
    for (int kk = 0; kk < 4; kk++) {
        const float4* p0 = (const float4*)(qrow + g * 8 + kk * 32);
        float4 u = p0[0], v = p0[1];
        bf16x8 t;
        t[0] = (__bf16)(u.x * SCALE); t[1] = (__bf16)(u.y * SCALE);
        t[2] = (__bf16)(u.z * SCALE); t[3] = (__bf16)(u.w * SCALE);
        t[4] = (__bf16)(v.x * SCALE); t[5] = (__bf16)(v.y * SCALE);
        t[6] = (__bf16)(v.z * SCALE); t[7] = (__bf16)(v.w * SCALE);
        qf[kk] = t;
    }

    float m[4], l[4];
#pragma unroll
    for (int r = 0; r < 4; r++) { m[r] = -1e30f; l[r] = 0.0f; }

    const int f  = tid & 31;
    const int r0 = tid >> 5;

    for (int kt = 0; kt < 16; kt++) {
        const float* ktile = K + ((size_t)b * NSEQ + ks * 1024 + kt * 64) * DHEAD;
#pragma unroll
        for (int i = 0; i < 8; i++) {
            int r = r0 + i * 8;
            float4 u = *(const float4*)(ktile + (size_t)r * DHEAD + f * 4);
            *(unsigned long long*)(Klds + r * 256 + ((f * 8) ^ ((r & 7) << 4))) = pack4(u);
        }
        __syncthreads();

        f32x4 acc[4];
#pragma unroll
        for (int n = 0; n < 4; n++) acc[n] = (f32x4){0.f, 0.f, 0.f, 0.f};
#pragma unroll
        for (int n = 0; n < 4; n++) {
            int row = n * 16 + c;
#pragma unroll
            for (int kk = 0; kk < 4; kk++) {
                bf16x8 kf = *(const bf16x8*)(Klds + row * 256 +
                                ((g * 16 + kk * 64) ^ ((row & 7) << 4)));
                acc[n] = __builtin_amdgcn_mfma_f32_16x16x32_bf16(qf[kk], kf, acc[n], 0, 0, 0);
            }
        }

#pragma unroll
        for (int r = 0; r < 4; r++) {
            float t = fmaxf(fmaxf(acc[0][r], acc[1][r]), fmaxf(acc[2][r], acc[3][r]));
            t = fmaxf(t, __shfl_xor(t, 1));
            t = fmaxf(t, __shfl_xor(t, 2));
            t = fmaxf(t, __shfl_xor(t, 4));
            t = fmaxf(t, __shfl_xor(t, 8));
            float mn = fmaxf(m[r], t);
            float sc = __expf(m[r] - mn);
            float ps = __expf(acc[0][r] - mn) + __expf(acc[1][r] - mn)
                     + __expf(acc[2][r] - mn) + __expf(acc[3][r] - mn);
            ps += __shfl_xor(ps, 1);
            ps += __shfl_xor(ps, 2);
            ps += __shfl_xor(ps, 4);
            ps += __shfl_xor(ps, 8);
            l[r] = l[r] * sc + ps;
            m[r] = mn;
        }
        __syncthreads();
    }

    if (c == 0) {
#pragma unroll
        for (int r = 0; r < 4; r++) {
            size_t row = rowbase + w * 16 + g * 4 + r;
            float* p = pbase + ((size_t)b * NSEQ + row) * pstride + ks * 2;
            p[0] = m[r];
            p[1] = l[r];
        }
    }
}

extern "C" __global__ __launch_bounds__(512, 2)
void attn_final_fb(const float* __restrict__ K, const float* __restrict__ Q,
                   const float* __restrict__ V, float* __restrict__ out)
{
    __shared__ __align__(16) char LDS[81920];

    const int bid = blockIdx.x;
    const int rt  = bid & 63;
    const int b   = bid >> 6;
    const int tid = threadIdx.x;
    const int rowbase = rt * 64;
    const int lane = tid & 63;
    const int w    = tid >> 6;
    const int rw   = w & 3;
    const int grp  = w >> 2;
    const int g    = lane >> 4;
    const int c    = lane & 15;
    const int t    = tid & 255;

    float* ctxOut = out;
    float* attn   = out + (size_t)BDIM * NSEQ * DHEAD;

    char* Klds  = LDS + grp * 16384;
    char* Vtlds = LDS + 32768 + grp * 16384;
    char* Plds  = LDS + 65536 + w * 2048;

    float Cq;
    {
        const float* prow = attn + ((size_t)b * NSEQ + rowbase + rw * 16 + c) * NSEQ;
        float4 p0 = *(const float4*)prow;
        float4 p1 = *(const float4*)(prow + 4);
        float M = fmaxf(fmaxf(p0.x, p0.z), fmaxf(p1.x, p1.z));
        float L = p0.y * __expf(p0.x - M) + p0.w * __expf(p0.z - M)
                + p1.y * __expf(p1.x - M) + p1.w * __expf(p1.z - M);
        Cq = M + __logf(L);
    }

    const float* qrow = Q + ((size_t)b * NSEQ + rowbase + rw * 16 + c) * DHEAD;
    bf16x8 qf[4];
#pragma unroll
    for (int kk = 0; kk < 4; kk++) {
        const float4* p0 = (const float4*)(qrow + g * 8 + kk * 32);
        float4 u = p0[0], v = p0[1];
        bf16x8 tt;
        tt[0] = (__bf16)(u.x * SCALE); tt[1] = (__bf16)(u.y * SCALE);
        tt[2] = (__bf16)(u.z * SCALE); tt[3] = (__bf16)(u.w * SCALE);
        tt[4] = (__bf16)(v.x * SCALE); tt[5] = (__bf16)(v.y * SCALE);
        tt[6] = (__bf16)(v.z * SCALE); tt[7] = (__bf16)(v.w * SCALE);
        qf[kk] = tt;
    }

    f32x4 ctx[8];
#pragma unroll
    for (int n2 = 0; n2 < 8; n2++) ctx[n2] = (f32x4){0.f, 0.f, 0.f, 0.f};

    __syncthreads();

    const int fK = t & 31;
    const int rK = t >> 5;
    const int dq = t & 15;
    const int kb = t >> 4;
    const int k0 = kb * 4;
    const int d0 = dq * 2;

    const float* kbase = K + ((size_t)b * NSEQ + grp * 2048) * DHEAD;
    const float* vbase = V + ((size_t)b * NSEQ + grp * 2048) * DHEAD;

    float4 kreg[8];
    float2 vreg[4][4];

#pragma unroll
    for (int i = 0; i < 8; i++)
        kreg[i] = *(const float4*)(kbase + (size_t)(rK + i * 8) * DHEAD + fK * 4);
#pragma unroll
    for (int i = 0; i < 4; i++)
#pragma unroll
        for (int j = 0; j < 4; j++)
            vreg[i][j] = *(const float2*)(vbase + (size_t)(k0 + j) * DHEAD + d0 + 32 * i);

    for (int kt = 0; kt < 32; kt++) {
        __builtin_amdgcn_s_barrier();

#pragma unroll
        for (int i = 0; i < 8; i++) {
            int row = rK + i * 8;
            *(unsigned long long*)(Klds + row * 256 + ((fK * 8) ^ ((row & 7) << 4))) = pack4(kreg[i]);
        }
#pragma unroll
        for (int i = 0; i < 4; i++) {
            int d = d0 + 32 * i;
            unsigned long long rr0 =
                (unsigned long long)f2bf(vreg[i][0].x)
              | ((unsigned long long)f2bf(vreg[i][1].x) << 16)
              | ((unsigned long long)f2bf(vreg[i][2].x) << 32)
              | ((unsigned long long)f2bf(vreg[i][3].x) << 48);
            unsigned long long rr1 =
                (unsigned long long)f2bf(vreg[i][0].y)
              | ((unsigned long long)f2bf(vreg[i][1].y) << 16)
              | ((unsigned long long)f2bf(vreg[i][2].y) << 32)
              | ((unsigned long long)f2bf(vreg[i][3].y) << 48);
            int swz = (d & 7) << 4;
            *(unsigned long long*)(Vtlds + d * 128 + ((k0 * 2) ^ swz)) = rr0;
            *(unsigned long long*)(Vtlds + (d + 1) * 128 + ((k0 * 2) ^ (swz + 16))) = rr1;
        }
        asm volatile("s_waitcnt lgkmcnt(0)" ::: "memory");
        __builtin_amdgcn_s_barrier();

        {
            int kn = (kt + 1) & 31;
            const float* kp = kbase + (size_t)kn * 64 * DHEAD;
            const float* vp = vbase + (size_t)kn * 64 * DHEAD;
#pragma unroll
            for (int i = 0; i < 8; i++)
                kreg[i] = *(const float4*)(kp + (size_t)(rK + i * 8) * DHEAD + fK * 4);
#pragma unroll
            for (int i = 0; i < 4; i++)
#pragma unroll
                for (int j = 0; j < 4; j++)
                    vreg[i][j] = *(const float2*)(vp + (size_t)(k0 + j) * DHEAD + d0 + 32 * i);
        }

        f32x4 sacc[4];
#pragma unroll
        for (int nt = 0; nt < 4; nt++) sacc[nt] = (f32x4){0.f, 0.f, 0.f, 0.f};
        __builtin_amdgcn_s_setprio(1);
#pragma unroll
        for (int nt = 0; nt < 4; nt++) {
            int row = nt * 16 + c;
#pragma unroll
            for (int kk = 0; kk < 4; kk++) {
                bf16x8 kf = *(const bf16x8*)(Klds + row * 256 +
                                ((g * 16 + kk * 64) ^ ((row & 7) << 4)));
                sacc[nt] = __builtin_amdgcn_mfma_f32_16x16x32_bf16(kf, qf[kk], sacc[nt], 0, 0, 0);
            }
        }
        __builtin_amdgcn_s_setprio(0);

        const int col0 = grp * 2048 + kt * 64;
        float* arow = attn + ((size_t)b * NSEQ + rowbase + rw * 16 + c) * NSEQ + col0;
#pragma unroll
        for (int nt = 0; nt < 4; nt++) {
            float4 pv;
            pv.x = __expf(sacc[nt][0] - Cq);
            pv.y = __expf(sacc[nt][1] - Cq);
            pv.z = __expf(sacc[nt][2] - Cq);
            pv.w = __expf(sacc[nt][3] - Cq);
            *(float4*)(arow + nt * 16 + g * 4) = pv;
            *(unsigned long long*)(Plds + c * 128 +
                ((nt * 32 + g * 8) ^ ((c & 7) << 4))) = pack4(pv);
        }
        asm volatile("s_waitcnt lgkmcnt(0)" ::: "memory");
        __builtin_amdgcn_sched_barrier(0);

        bf16x8 pf[2];
#pragma unroll
        for (int kk = 0; kk < 2; kk++)
            pf[kk] = *(const bf16x8*)(Plds + c * 128 +
                        ((kk * 64 + g * 16) ^ ((c & 7) << 4)));

        __builtin_amdgcn_s_setprio(1);
#pragma unroll
        for (int n2 = 0; n2 < 8; n2++) {
            int d = n2 * 16 + c;
#pragma unroll
            for (int kk = 0; kk < 2; kk++) {
                bf16x8 vff = *(const bf16x8*)(Vtlds + d * 128 +
                                ((kk * 64 + g * 16) ^ ((d & 7) << 4)));
                ctx[n2] = __builtin_amdgcn_mfma_f32_16x16x32_bf16(pf[kk], vff, ctx[n2], 0, 0, 0);
            }
        }
        __builtin_amdgcn_s_setprio(0);
    }

    __syncthreads();

    float* red = (float*)LDS;
    if (grp == 1) {
#pragma unroll
        for (int n2 = 0; n2 < 8; n2++)
#pragma unroll
            for (int r = 0; r < 4; r++)
                red[(rw * 16 + g * 4 + r) * 128 + n2 * 16 + c] = ctx[n2][r];
    }
    __syncthreads();
    if (grp == 0) {
#pragma unroll
        for (int n2 = 0; n2 < 8; n2++)
#pragma unroll
            for (int r = 0; r < 4; r++) {
                size_t row = rowbase + rw * 16 + g * 4 + r;
                ctxOut[((size_t)b * NSEQ + row) * DHEAD + n2 * 16 + c] =
                    ctx[n2][r] + red[(rw * 16 + g * 4 + r) * 128 + n2 * 16 + c];
            }
    }
}

extern "C" void kernel_launch(void* const* d_in, const int* in_sizes, int n_in,
                              void* d_out, int out_size, void* d_ws, size_t ws_size,
                              hipStream_t stream)
{
    const float* K = (const float*)d_in[0];   // "key"
    const float* Q = (const float*)d_in[1];   // "query"
    const float* V = (const float*)d_in[2];   // "value"
    float* out  = (float*)d_out;
    float* attn = out + (size_t)BDIM * NSEQ * DHEAD;

    const size_t ctx_bytes = (size_t)BDIM * NSEQ * DHEAD * sizeof(float);  // 8 MB
    const size_t need      = (9u << 20) + 8 * ctx_bytes;                   // 73 MB

    if (ws_size >= need) {
        char* ws = (char*)d_ws;
        float* part = (float*)(ws + (9u << 20));
        stats_repack<<<dim3(1024 + 512), dim3(256), 0, stream>>>(K, Q, V, ws);
        attn_mf2<<<dim3(1024), dim3(256), 0, stream>>>(ws, Q, out, part);
        ctx_reduce8<<<dim3(2048), dim3(256), 0, stream>>>((const float4*)part, (float4*)out);
    } else {
        attn_stats_fb<<<dim3(4 * 64 * 4), dim3(256), 0, stream>>>(K, Q, attn, NSEQ);
        attn_final_fb<<<dim3(4 * 64), dim3(512), 0, stream>>>(K, Q, V, out);
    }
}